// Round 5
// baseline (40813.464 us; speedup 1.0000x reference)
//
#include <hip/hip_runtime.h>
#include <stdint.h>

#define NBLK 256
#define NTHR 512          // 8 waves
#define BATCH 64
#define HD 1024
#define SEQ 512

typedef unsigned short u16;
typedef uint32_t u32;
typedef __attribute__((ext_vector_type(8))) short v8s;        // 8 bf16 (MFMA A/B frag)
typedef __attribute__((ext_vector_type(4))) float v4f;        // MFMA C/D frag
typedef __attribute__((ext_vector_type(4))) unsigned int v4u; // dwordx4

__device__ __forceinline__ float bf2f(u16 u){
  union { float f; u32 i; } c; c.i = ((u32)u) << 16; return c.f;
}
__device__ __forceinline__ u16 f2bf(float f){  // round-to-nearest-even
  union { float f; u32 i; } c; c.f = f;
  u32 i = c.i;
  return (u16)((i + 0x7fffu + ((i >> 16) & 1u)) >> 16);
}
__device__ __forceinline__ float sigm(float v){ return 1.f / (1.f + __expf(-v)); }

// packed activation element: low16 = hi bf16, high16 = lo bf16; value = hi + lo
__device__ __forceinline__ u32 packf(float v){
  const u16 hi = f2bf(v);
  const u16 lo = f2bf(v - bf2f(hi));
  return (u32)hi | ((u32)lo << 16);
}
__device__ __forceinline__ float unpackf(u32 w){
  return bf2f((u16)(w & 0xffffu)) + bf2f((u16)(w >> 16));
}

// ---- UC (MALL-coherent) ops: always correct across XCDs ----
__device__ __forceinline__ void ast(u32* p, u32 v){
  __hip_atomic_store(p, v, __ATOMIC_RELAXED, __HIP_MEMORY_SCOPE_AGENT);
}
__device__ __forceinline__ void asti(int* p, int v){
  __hip_atomic_store(p, v, __ATOMIC_RELAXED, __HIP_MEMORY_SCOPE_AGENT);
}
__device__ __forceinline__ int aldi(const int* p){
  return __hip_atomic_load(p, __ATOMIC_RELAXED, __HIP_MEMORY_SCOPE_AGENT);
}
__device__ __forceinline__ u32 aldu(const u32* p){
  return __hip_atomic_load(p, __ATOMIC_RELAXED, __HIP_MEMORY_SCOPE_AGENT);
}

// ---- L2-scope loads: sc0 = bypass L1, served by the XCD's L2 ----
__device__ __forceinline__ u32 l2_ldu(const u32* p){
  u32 r;
  asm volatile("global_load_dword %0, %1, off sc0\n\ts_waitcnt vmcnt(0)"
               : "=v"(r) : "v"(p) : "memory");
  return r;
}
// A-frag pattern: per 32-elem k-step, lane reads 8 consecutive u32 (32 B)
__device__ __forceinline__ void l2_batch8(const u32* p, v4u r[8]){
  asm volatile(
    "global_load_dwordx4 %0, %8, off sc0\n\t"
    "global_load_dwordx4 %1, %8, off offset:16 sc0\n\t"
    "global_load_dwordx4 %2, %8, off offset:128 sc0\n\t"
    "global_load_dwordx4 %3, %8, off offset:144 sc0\n\t"
    "global_load_dwordx4 %4, %8, off offset:256 sc0\n\t"
    "global_load_dwordx4 %5, %8, off offset:272 sc0\n\t"
    "global_load_dwordx4 %6, %8, off offset:384 sc0\n\t"
    "global_load_dwordx4 %7, %8, off offset:400 sc0\n\t"
    "s_waitcnt vmcnt(0)"
    : "=&v"(r[0]), "=&v"(r[1]), "=&v"(r[2]), "=&v"(r[3]),
      "=&v"(r[4]), "=&v"(r[5]), "=&v"(r[6]), "=&v"(r[7])
    : "v"(p) : "memory");
}
__device__ __forceinline__ void l2_batch16(const u32* p, v4u r[16]){
  asm volatile(
    "global_load_dwordx4 %0, %16, off sc0\n\t"
    "global_load_dwordx4 %1, %16, off offset:16 sc0\n\t"
    "global_load_dwordx4 %2, %16, off offset:128 sc0\n\t"
    "global_load_dwordx4 %3, %16, off offset:144 sc0\n\t"
    "global_load_dwordx4 %4, %16, off offset:256 sc0\n\t"
    "global_load_dwordx4 %5, %16, off offset:272 sc0\n\t"
    "global_load_dwordx4 %6, %16, off offset:384 sc0\n\t"
    "global_load_dwordx4 %7, %16, off offset:400 sc0\n\t"
    "global_load_dwordx4 %8, %16, off offset:512 sc0\n\t"
    "global_load_dwordx4 %9, %16, off offset:528 sc0\n\t"
    "global_load_dwordx4 %10, %16, off offset:640 sc0\n\t"
    "global_load_dwordx4 %11, %16, off offset:656 sc0\n\t"
    "global_load_dwordx4 %12, %16, off offset:768 sc0\n\t"
    "global_load_dwordx4 %13, %16, off offset:784 sc0\n\t"
    "global_load_dwordx4 %14, %16, off offset:896 sc0\n\t"
    "global_load_dwordx4 %15, %16, off offset:912 sc0\n\t"
    "s_waitcnt vmcnt(0)"
    : "=&v"(r[0]), "=&v"(r[1]), "=&v"(r[2]), "=&v"(r[3]),
      "=&v"(r[4]), "=&v"(r[5]), "=&v"(r[6]), "=&v"(r[7]),
      "=&v"(r[8]), "=&v"(r[9]), "=&v"(r[10]), "=&v"(r[11]),
      "=&v"(r[12]), "=&v"(r[13]), "=&v"(r[14]), "=&v"(r[15])
    : "v"(p) : "memory");
}
// fetcher: 128 contiguous bytes, UC
__device__ __forceinline__ void uc_fetch8(const u32* p, v4u r[8]){
  asm volatile(
    "global_load_dwordx4 %0, %8, off sc0 sc1\n\t"
    "global_load_dwordx4 %1, %8, off offset:16 sc0 sc1\n\t"
    "global_load_dwordx4 %2, %8, off offset:32 sc0 sc1\n\t"
    "global_load_dwordx4 %3, %8, off offset:48 sc0 sc1\n\t"
    "global_load_dwordx4 %4, %8, off offset:64 sc0 sc1\n\t"
    "global_load_dwordx4 %5, %8, off offset:80 sc0 sc1\n\t"
    "global_load_dwordx4 %6, %8, off offset:96 sc0 sc1\n\t"
    "global_load_dwordx4 %7, %8, off offset:112 sc0 sc1\n\t"
    "s_waitcnt vmcnt(0)"
    : "=&v"(r[0]), "=&v"(r[1]), "=&v"(r[2]), "=&v"(r[3]),
      "=&v"(r[4]), "=&v"(r[5]), "=&v"(r[6]), "=&v"(r[7])
    : "v"(p) : "memory");
}

struct FragPair { v8s hi; v8s lo; };
__device__ __forceinline__ FragPair splitpair(v4u w0, v4u w1){
  union { v8s v; u32 u[4]; } H, L;
#pragma unroll
  for (int i = 0; i < 2; i++){
    H.u[i]     = (w0[2*i] & 0xffffu) | (w0[2*i+1] << 16);
    L.u[i]     = (w0[2*i] >> 16)     | (w0[2*i+1] & 0xffff0000u);
    H.u[2 + i] = (w1[2*i] & 0xffffu) | (w1[2*i+1] << 16);
    L.u[2 + i] = (w1[2*i] >> 16)     | (w1[2*i+1] & 0xffff0000u);
  }
  FragPair f; f.hi = H.v; f.lo = L.v; return f;
}

// ---- full-grid barrier (prep only) ----
__device__ __forceinline__ void gbar_all(int* flags, int target, int bid, int tid){
  __syncthreads();
  if (tid == 0) asti(&flags[bid], target);
  if (tid < 64){
    const int* p = flags + tid * 4;
    for (;;){
      int a = aldi(p + 0), b = aldi(p + 1), c = aldi(p + 2), d = aldi(p + 3);
      if (a >= target && b >= target && c >= target && d >= target) break;
      __builtin_amdgcn_s_sleep(1);
    }
  }
  __syncthreads();
}

// ---- phase exchange: producers -> UC staging -> per-XCD L2 mirror ----
// Members post gflag (UC). Fetcher (first block of its (group,XCD)) polls all
// 64 member flags (UC), pulls the group's 16x1024 u32 tile once from the MALL,
// re-stores it into the XCD-private mirror (plain stores -> local L2), posts
// lflag via UC. Members poll lflag (UC) then read mirror via sc0 (L2 hits).
__device__ __forceinline__ void exchange(int bar, const u32* Og, u32* mir, int rm,
                                         bool isF, int* gflag, int* lf,
                                         int member, int tid){
  __syncthreads();                       // drain producers' UC data stores
  if (tid == 0) asti(&gflag[member], bar);
  if (isF){
    if (tid < 64){
      for (;;){
        int v = aldi(&gflag[tid]);
        if (__all(v >= bar)) break;
        __builtin_amdgcn_s_sleep(1);
      }
    }
    __syncthreads();
    const int row = tid >> 5, c0 = (tid & 31) << 5;   // 512 thr = 16 rows x 32 chunks
    v4u r[8];
    uc_fetch8(Og + (size_t)(rm + row) * HD + c0, r);
    v4u* d = (v4u*)(mir + row * HD + c0);
#pragma unroll
    for (int i = 0; i < 8; i++) d[i] = r[i];
    __syncthreads();                     // mirror stores drained into local L2
    if (tid == 0) asti(lf, bar);         // UC post (line-sharing safe)
  } else {
    if (tid < 64){
      while (aldi(lf) < bar) __builtin_amdgcn_s_sleep(1);
    }
    __syncthreads();
  }
}

// ---- pre-barrier weight prefetch ----
struct MogPre { v8s bh0, bl0, bh1, bl1; };
__device__ __forceinline__ MogPre mog_pre(const u16* WThi, const u16* WTlo, int cn, int tid){
  const int w = tid >> 6, lane = tid & 63;
  const int mi = lane & 15, q = lane >> 4;
  const int kb = w * 128 + q * 8;
  const u16* bh_p = WThi + (size_t)(cn + mi) * HD + kb;
  const u16* bl_p = WTlo + (size_t)(cn + mi) * HD + kb;
  MogPre pre;
  pre.bh0 = *(const v8s*)(bh_p);       pre.bl0 = *(const v8s*)(bl_p);
  pre.bh1 = *(const v8s*)(bh_p + 32);  pre.bl1 = *(const v8s*)(bl_p + 32);
  return pre;
}
struct GatesPre { v8s bh[4]; v8s bl[4]; };
__device__ __forceinline__ GatesPre gates_pre(
    const u16* WihThi, const u16* WihTlo,
    const u16* WhhThi, const u16* WhhTlo, int cn, int tid){
  const int w = tid >> 6, lane = tid & 63;
  const int mi = lane & 15;
  const int src = w >> 2;
  const u16* Bh = src ? WhhThi : WihThi;
  const u16* Bl = src ? WhhTlo : WihTlo;
  const int kb = (w & 3) * 256 + (lane >> 4) * 8;
  GatesPre g;
#pragma unroll
  for (int nt = 0; nt < 4; nt++){
    const size_t brow = (size_t)(nt * HD + cn + mi) * HD + kb;
    g.bh[nt] = *(const v8s*)(Bh + brow);
    g.bl[nt] = *(const v8s*)(Bl + brow);
  }
  return g;
}

// ---- one mogrify matmul phase: O = 2*sigmoid(A @ W) * mult ----
// A and M from the XCD-local mirror (L2, sc0); O to UC staging.
__device__ __forceinline__ void mog_phase(
    MogPre pre, const u32* mirA,
    const u16* WThi, const u16* WTlo,
    const float* multx, const u32* mirM, u32* Og,
    int rm, int cn, int tid, float* cb)
{
  const int w = tid >> 6, lane = tid & 63;
  const int mi = lane & 15, q = lane >> 4;
  const int kb = w * 128 + q * 8;
  const int er = tid >> 4, ec = tid & 15;
  const bool epi = (tid < 256);
  float multv = 0.f; u32 mpack = 0;
  if (epi){
    if (multx) multv = __builtin_nontemporal_load(multx + (size_t)(rm + er) * (SEQ * HD) + (cn + ec));
    else       mpack = l2_ldu(mirM + er * HD + (cn + ec));
  }
  const u16* bh_p = WThi + (size_t)(cn + mi) * HD + kb;
  const u16* bl_p = WTlo + (size_t)(cn + mi) * HD + kb;
  v8s bh2 = *(const v8s*)(bh_p + 64), bl2 = *(const v8s*)(bl_p + 64);
  v8s bh3 = *(const v8s*)(bh_p + 96), bl3 = *(const v8s*)(bl_p + 96);
  v4u ar[8];
  l2_batch8(mirA + mi * HD + kb, ar);

  v4f acc = {0.f, 0.f, 0.f, 0.f};
  FragPair a0 = splitpair(ar[0], ar[1]);
  acc = __builtin_amdgcn_mfma_f32_16x16x32_bf16(a0.hi, pre.bh0, acc, 0, 0, 0);
  acc = __builtin_amdgcn_mfma_f32_16x16x32_bf16(a0.hi, pre.bl0, acc, 0, 0, 0);
  acc = __builtin_amdgcn_mfma_f32_16x16x32_bf16(a0.lo, pre.bh0, acc, 0, 0, 0);
  FragPair a1 = splitpair(ar[2], ar[3]);
  acc = __builtin_amdgcn_mfma_f32_16x16x32_bf16(a1.hi, pre.bh1, acc, 0, 0, 0);
  acc = __builtin_amdgcn_mfma_f32_16x16x32_bf16(a1.hi, pre.bl1, acc, 0, 0, 0);
  acc = __builtin_amdgcn_mfma_f32_16x16x32_bf16(a1.lo, pre.bh1, acc, 0, 0, 0);
  FragPair a2 = splitpair(ar[4], ar[5]);
  acc = __builtin_amdgcn_mfma_f32_16x16x32_bf16(a2.hi, bh2, acc, 0, 0, 0);
  acc = __builtin_amdgcn_mfma_f32_16x16x32_bf16(a2.hi, bl2, acc, 0, 0, 0);
  acc = __builtin_amdgcn_mfma_f32_16x16x32_bf16(a2.lo, bh2, acc, 0, 0, 0);
  FragPair a3 = splitpair(ar[6], ar[7]);
  acc = __builtin_amdgcn_mfma_f32_16x16x32_bf16(a3.hi, bh3, acc, 0, 0, 0);
  acc = __builtin_amdgcn_mfma_f32_16x16x32_bf16(a3.hi, bl3, acc, 0, 0, 0);
  acc = __builtin_amdgcn_mfma_f32_16x16x32_bf16(a3.lo, bh3, acc, 0, 0, 0);

  float* dst = cb + w * 1088;            // [w][16][17] partials
#pragma unroll
  for (int r = 0; r < 4; r++) dst[(q * 4 + r) * 17 + mi] = acc[r];
  __syncthreads();
  if (epi){
    float v = 0.f;
#pragma unroll
    for (int w2 = 0; w2 < 8; w2++) v += cb[w2 * 1088 + er * 17 + ec];
    const float mult = multx ? multv : unpackf(mpack);
    ast(Og + (rm + er) * HD + (cn + ec), packf(2.f * sigm(v) * mult));
  }
}

// ---- gates + fused LSTM cell (A operands from mirrors) ----
__device__ __forceinline__ void gates_phase(
    GatesPre gp, const u32* mirX, const u32* mirH,
    const u16* WihThi, const u16* WihTlo,
    const u16* WhhThi, const u16* WhhTlo,
    const float* bsum, float& creg, u32* Og, float* outp,
    int rm, int cn, int tid, float* cb, float* red)
{
  const int w = tid >> 6, lane = tid & 63;
  const int mi = lane & 15, q = lane >> 4;
  const int src = w >> 2;
  const u32* Ap = src ? mirH : mirX;
  const u16* Bh = src ? WhhThi : WihThi;
  const u16* Bl = src ? WhhTlo : WihTlo;
  const int kb = (w & 3) * 256 + q * 8;
  v4u ar[16];
  l2_batch16(Ap + mi * HD + kb, ar);

  const u16* bh_p[4]; const u16* bl_p[4];
#pragma unroll
  for (int nt = 0; nt < 4; nt++){
    const size_t brow = (size_t)(nt * HD + cn + mi) * HD + kb;
    bh_p[nt] = Bh + brow; bl_p[nt] = Bl + brow;
  }
  v4f acc[4];
#pragma unroll
  for (int nt = 0; nt < 4; nt++) acc[nt] = (v4f){0.f, 0.f, 0.f, 0.f};
  {
    FragPair a = splitpair(ar[0], ar[1]);
#pragma unroll
    for (int nt = 0; nt < 4; nt++){
      acc[nt] = __builtin_amdgcn_mfma_f32_16x16x32_bf16(a.hi, gp.bh[nt], acc[nt], 0, 0, 0);
      acc[nt] = __builtin_amdgcn_mfma_f32_16x16x32_bf16(a.hi, gp.bl[nt], acc[nt], 0, 0, 0);
      acc[nt] = __builtin_amdgcn_mfma_f32_16x16x32_bf16(a.lo, gp.bh[nt], acc[nt], 0, 0, 0);
    }
  }
#pragma unroll
  for (int ks = 1; ks < 8; ks++){
    const int k = ks * 32;
    FragPair a = splitpair(ar[2 * ks], ar[2 * ks + 1]);
#pragma unroll
    for (int nt = 0; nt < 4; nt++){
      v8s bh = *(const v8s*)(bh_p[nt] + k);
      v8s bl = *(const v8s*)(bl_p[nt] + k);
      acc[nt] = __builtin_amdgcn_mfma_f32_16x16x32_bf16(a.hi, bh, acc[nt], 0, 0, 0);
      acc[nt] = __builtin_amdgcn_mfma_f32_16x16x32_bf16(a.hi, bl, acc[nt], 0, 0, 0);
      acc[nt] = __builtin_amdgcn_mfma_f32_16x16x32_bf16(a.lo, bh, acc[nt], 0, 0, 0);
    }
  }
#pragma unroll
  for (int nt = 0; nt < 4; nt++)
#pragma unroll
    for (int r = 0; r < 4; r++)
      cb[(w * 4 + nt) * 272 + (q * 4 + r) * 17 + mi] = acc[nt][r];
  __syncthreads();
  for (int e = tid; e < 1024; e += NTHR){
    const int qq = e >> 8, rc = e & 255, r = rc >> 4, c = rc & 15;
    float v = 0.f;
#pragma unroll
    for (int w2 = 0; w2 < 8; w2++) v += cb[(w2 * 4 + qq) * 272 + r * 17 + c];
    red[qq * 272 + r * 17 + c] = v;
  }
  __syncthreads();
  if (tid < 256){
    const int r = tid >> 4, c = tid & 15;
    const float g0 = red[0 * 272 + r * 17 + c] + bsum[0];
    const float g1 = red[1 * 272 + r * 17 + c] + bsum[1];
    const float g2 = red[2 * 272 + r * 17 + c] + bsum[2];
    const float g3 = red[3 * 272 + r * 17 + c] + bsum[3];
    const float ig = sigm(g0), fg = sigm(g1), cg = tanhf(g2), og = sigm(g3);
    const float cnew = fg * creg + ig * cg;
    creg = cnew;
    const float h = og * tanhf(cnew);
    if (outp) outp[(rm + r) * HD + (cn + c)] = h;            // final step
    else      ast(Og + (rm + r) * HD + (cn + c), packf(h));
  }
}

extern "C" __global__ void __launch_bounds__(NTHR, 2)
moglstm_kernel(const float* __restrict__ x, const float* __restrict__ Wih,
               const float* __restrict__ Whh, const float* __restrict__ bih,
               const float* __restrict__ bhh, const float* __restrict__ Q,
               const float* __restrict__ Rw, const float* __restrict__ h0,
               const float* __restrict__ c0, float* __restrict__ out,
               uint8_t* __restrict__ ws)
{
  __shared__ float cb[32 * 272];
  __shared__ float red[4 * 272];
  __shared__ u16 shh[32 * 33], shl[32 * 33];
  __shared__ int s_isF;

  // ---- carve workspace (~44.6 MB) ----
  uint8_t* p = ws;
  u32* xg   = (u32*)p;     p += (size_t)BATCH * HD * 4;        // x staging (UC)
  u32* hg   = (u32*)p;     p += (size_t)BATCH * HD * 4;        // h staging (UC)
  u16* QThi  = (u16*)p;    p += (size_t)HD * HD * 2;
  u16* QTlo  = (u16*)p;    p += (size_t)HD * HD * 2;
  u16* RThi  = (u16*)p;    p += (size_t)HD * HD * 2;
  u16* RTlo  = (u16*)p;    p += (size_t)HD * HD * 2;
  u16* WihThi = (u16*)p;   p += (size_t)4 * HD * HD * 2;
  u16* WihTlo = (u16*)p;   p += (size_t)4 * HD * HD * 2;
  u16* WhhThi = (u16*)p;   p += (size_t)4 * HD * HD * 2;
  u16* WhhTlo = (u16*)p;   p += (size_t)4 * HD * HD * 2;
  int* flagsP = (int*)p;   p += 256 * 4;          // prep barrier flags
  int* gflags = (int*)p;   p += 4 * 64 * 4;       // [group][member] (UC)
  int* lflags = (int*)p;   p += 4 * 8 * 32 * 4;   // [group][xcd], 128-B stride (UC)
  int* cnt    = (int*)p;   p += 4 * 8 * 4;        // roster counters (UC)
  p = (uint8_t*)(((uintptr_t)p + 255) & ~(uintptr_t)255);
  const size_t MSLOT = (size_t)4 * 8 * 16 * HD;   // [group][xcd][16][1024] u32
  u32* mirX = (u32*)p;     p += MSLOT * 4;        // 2 MB
  u32* mirH = (u32*)p;     p += MSLOT * 4;        // 2 MB

  const int bid = blockIdx.x, tid = threadIdx.x;
  const int group = bid >> 6, member = bid & 63;
  const int rm = group * 16, cn = member * 16;

  // ---- prep: split weights into hi/lo bf16 + transpose to WT[n][k]; init h ----
  for (int tile = bid; tile < 10240; tile += NBLK){
    const float* W; u16 *Th, *Tl; int N, kt, nt;
    if (tile < 1024)      { W = Q;   Th = QThi;   Tl = QTlo;   N = HD;     int tl = tile;        kt = tl >> 5; nt = tl & 31; }
    else if (tile < 2048) { W = Rw;  Th = RThi;   Tl = RTlo;   N = HD;     int tl = tile - 1024; kt = tl >> 5; nt = tl & 31; }
    else if (tile < 6144) { W = Wih; Th = WihThi; Tl = WihTlo; N = 4 * HD; int tl = tile - 2048; kt = tl >> 7; nt = tl & 127; }
    else                  { W = Whh; Th = WhhThi; Tl = WhhTlo; N = 4 * HD; int tl = tile - 6144; kt = tl >> 7; nt = tl & 127; }
    for (int e = tid; e < 1024; e += NTHR){
      const int ki = e >> 5, nj = e & 31;
      const float v = W[(size_t)(kt * 32 + ki) * N + nt * 32 + nj];
      const u16 hi = f2bf(v);
      shh[ki * 33 + nj] = hi;
      shl[ki * 33 + nj] = f2bf(v - bf2f(hi));
    }
    __syncthreads();
    for (int e = tid; e < 1024; e += NTHR){
      const int ni = e >> 5, kj = e & 31;
      Th[(size_t)(nt * 32 + ni) * HD + kt * 32 + kj] = shh[kj * 33 + ni];
      Tl[(size_t)(nt * 32 + ni) * HD + kt * 32 + kj] = shl[kj * 33 + ni];
    }
    __syncthreads();
  }
  // init h staging (UC so fetchers see it)
  for (int i = bid * NTHR + tid; i < BATCH * HD; i += NBLK * NTHR)
    ast(&hg[i], packf(h0[i]));
  // zero roster counters (UC) before anyone's fetch_add (ordered by grid barrier)
  if (bid == 0 && tid < 32) asti(&cnt[tid], 0);

  // hoist cell state + bias sums into registers (block<->tile mapping fixed)
  float creg = 0.f;
  float bsum[4] = {0.f, 0.f, 0.f, 0.f};
  if (tid < 256){
    const int r = tid >> 4, c = tid & 15, col = cn + c;
    creg = c0[(rm + r) * HD + col];
#pragma unroll
    for (int qq = 0; qq < 4; qq++) bsum[qq] = bih[qq * HD + col] + bhh[qq * HD + col];
  }

  // flush prep's plain weight stores to the coherent point, then grid barrier
  __threadfence();
  gbar_all(flagsP, 1, bid, tid);

  // ---- roster: discover my XCD; first block per (group,XCD) becomes fetcher ----
  int myxcd;
  asm volatile("s_getreg_b32 %0, hwreg(HW_REG_XCC_ID)" : "=s"(myxcd));
  myxcd &= 7;
  if (tid == 0){
    int r = __hip_atomic_fetch_add(&cnt[group * 8 + myxcd], 1,
                                   __ATOMIC_RELAXED, __HIP_MEMORY_SCOPE_AGENT);
    s_isF = (r == 0) ? 1 : 0;
  }
  __syncthreads();
  const bool isF = (s_isF != 0);
  int* gflag = gflags + group * 64;
  int* lf    = lflags + (group * 8 + myxcd) * 32;
  const size_t moff = (size_t)(group * 8 + myxcd) * 16 * HD;
  u32* m_x = mirX + moff;
  u32* m_h = mirH + moff;

  // ---- recurrence ----
  int bar = 1;
  exchange(bar, hg, m_h, rm, isF, gflag, lf, member, tid);   // mirror h0
  MogPre pre = mog_pre(QThi, QTlo, cn, tid);
  for (int t = 0; t < SEQ; t++){
    // p1: xt1 = 2s(ht0@Q)*x[:,t,:]  -> xg
    mog_phase(pre, m_h, QThi, QTlo, x + (size_t)t * HD, nullptr, xg, rm, cn, tid, cb);
    pre = mog_pre(RThi, RTlo, cn, tid);
    bar++; exchange(bar, xg, m_x, rm, isF, gflag, lf, member, tid);
    // p2: ht1 = 2s(xt1@R)*ht0  -> hg
    mog_phase(pre, m_x, RThi, RTlo, nullptr, m_h, hg, rm, cn, tid, cb);
    pre = mog_pre(QThi, QTlo, cn, tid);
    bar++; exchange(bar, hg, m_h, rm, isF, gflag, lf, member, tid);
    // p3: xt2 = 2s(ht1@Q)*xt1  -> xg
    mog_phase(pre, m_h, QThi, QTlo, nullptr, m_x, xg, rm, cn, tid, cb);
    pre = mog_pre(RThi, RTlo, cn, tid);
    bar++; exchange(bar, xg, m_x, rm, isF, gflag, lf, member, tid);
    // p4: ht2 = 2s(xt2@R)*ht1  -> hg
    mog_phase(pre, m_x, RThi, RTlo, nullptr, m_h, hg, rm, cn, tid, cb);
    pre = mog_pre(QThi, QTlo, cn, tid);
    bar++; exchange(bar, hg, m_h, rm, isF, gflag, lf, member, tid);
    // p5: xt3 = 2s(ht2@Q)*xt2  -> xg
    mog_phase(pre, m_h, QThi, QTlo, nullptr, m_x, xg, rm, cn, tid, cb);
    GatesPre gp = gates_pre(WihThi, WihTlo, WhhThi, WhhTlo, cn, tid);
    bar++; exchange(bar, xg, m_x, rm, isF, gflag, lf, member, tid);
    // gates + cell -> hg (or directly to out on the last step)
    gates_phase(gp, m_x, m_h, WihThi, WihTlo, WhhThi, WhhTlo, bsum, creg, hg,
                (t == SEQ - 1) ? out : nullptr, rm, cn, tid, cb, red);
    if (t < SEQ - 1){
      pre = mog_pre(QThi, QTlo, cn, tid);
      bar++; exchange(bar, hg, m_h, rm, isF, gflag, lf, member, tid);
    }
  }
}

extern "C" void kernel_launch(void* const* d_in, const int* in_sizes, int n_in,
                              void* d_out, int out_size, void* d_ws, size_t ws_size,
                              hipStream_t stream)
{
  const float* x   = (const float*)d_in[0];
  const float* Wih = (const float*)d_in[1];
  const float* Whh = (const float*)d_in[2];
  const float* bih = (const float*)d_in[3];
  const float* bhh = (const float*)d_in[4];
  const float* Q   = (const float*)d_in[5];
  const float* Rw  = (const float*)d_in[6];
  const float* h0  = (const float*)d_in[7];
  const float* c0  = (const float*)d_in[8];
  float* out = (float*)d_out;
  uint8_t* ws = (uint8_t*)d_ws;
  void* args[] = { &x, &Wih, &Whh, &bih, &bhh, &Q, &Rw, &h0, &c0, &out, &ws };
  hipLaunchCooperativeKernel((void*)moglstm_kernel, dim3(NBLK), dim3(NTHR),
                             args, 0, stream);
}